// Round 7
// baseline (1524.596 us; speedup 1.0000x reference)
//
// HNHN layer on MI355X (gfx950). Round 7: barrier-free register-pipelined MMs.
//  - MM cores: NO LDS, NO barriers. Per-lane global loads of MFMA frags for both
//    operands; B (stream) 4-deep register rotation, A (L2-hot Y) 2-deep; compiler
//    emits exact s_waitcnt vmcnt(N) for register deps (the AITER pattern in HIP).
//  - MM2 streams fp32 B1 directly (trunc-pack in VALU) -> b1h eliminated.
//  - k1 builds b1hT + rowsum only (536r+268w).
//  - XCD mapping: the two m-half blocks of a (sp,nb) sit 8 bids apart -> same XCD,
//    stream slab read once from HBM, second read from L2.
#include <hip/hip_runtime.h>
#include <stdint.h>

#define NN 16384
#define NE 8192
#define CH 256
#define MM1_SPLIT 4
#define MM2_SPLIT 2

typedef __attribute__((ext_vector_type(8))) short bf16x8;
typedef __attribute__((ext_vector_type(4))) float f32x4;

__device__ __forceinline__ unsigned short f2bf(float f) {  // RNE fp32->bf16
  unsigned u = __float_as_uint(f);
  u += 0x7FFFu + ((u >> 16) & 1u);
  return (unsigned short)(u >> 16);
}
__device__ __forceinline__ unsigned pack_trunc2(float a, float b) {  // exact for 0/1
  return (__float_as_uint(b) & 0xFFFF0000u) | (__float_as_uint(a) >> 16);
}
__device__ __forceinline__ void async_copy16(const void* gptr, void* lptr) {
  __builtin_amdgcn_global_load_lds((const __attribute__((address_space(1))) unsigned int*)gptr,
                                   (__attribute__((address_space(3))) unsigned int*)lptr,
                                   16, 0, 0);
}

// ---------------- K0: weight transpose to bf16 + rowsum zero ----------------
__global__ void k0_transpose_w(const float* __restrict__ W0, const float* __restrict__ W1,
                               unsigned short* __restrict__ W0T, unsigned short* __restrict__ W1T,
                               float* __restrict__ rowsum) {
  const float* W = blockIdx.y ? W1 : W0;
  unsigned short* WT = blockIdx.y ? W1T : W0T;
  int n = blockIdx.x;
  int k = threadIdx.x;
  WT[n * CH + k] = f2bf(W[k * CH + n]);
  if (blockIdx.y == 0 && blockIdx.x < NN / 256) rowsum[blockIdx.x * 256 + threadIdx.x] = 0.f;
}

// ---------------- K1: 128x128 tile: b1hT + rowsum atomics ----------------
__global__ __launch_bounds__(256) void k1_prep(const float* __restrict__ B1,
                                               unsigned short* __restrict__ b1hT,
                                               float* __restrict__ rowsum) {
  __shared__ unsigned short t16[128 * 136];
  __shared__ float rs[128][9];
  const int tid = threadIdx.x;
  const int e0 = blockIdx.x * 128;
  const int n0 = blockIdx.y * 128;
  const int rr = tid >> 3;        // 0..31
  const int ec = (tid & 7) * 16;  // e-chunk base (floats)
  float part[4];
#pragma unroll
  for (int rg = 0; rg < 4; ++rg) {
    int r = rg * 32 + rr;
    const float* src = B1 + (size_t)(n0 + r) * NE + e0 + ec;
    float s = 0.f;
    unsigned w[8];
#pragma unroll
    for (int u = 0; u < 4; ++u) {
      float4 v = *(const float4*)(src + u * 4);
      s += v.x + v.y + v.z + v.w;
      w[u * 2] = pack_trunc2(v.x, v.y);
      w[u * 2 + 1] = pack_trunc2(v.z, v.w);
    }
    part[rg] = s;
    unsigned* lp = (unsigned*)&t16[r * 136 + ec];
#pragma unroll
    for (int u = 0; u < 8; ++u) lp[u] = w[u];
  }
#pragma unroll
  for (int rg = 0; rg < 4; ++rg) rs[rg * 32 + rr][tid & 7] = part[rg];
  __syncthreads();
  if (tid < 128) {
    float s = 0.f;
#pragma unroll
    for (int u = 0; u < 8; ++u) s += rs[tid][u];
    atomicAdd(rowsum + n0 + tid, s);
  }
  // phase 2: write b1hT. thread: e-pair p (64), n-quarter h (4: 32 n each)
  const int p = tid & 63, h = tid >> 6;
  unsigned lo[16], hi[16];
#pragma unroll
  for (int u = 0; u < 16; ++u) {
    int n = h * 32 + u * 2;
    unsigned a = *(const unsigned*)&t16[n * 136 + p * 2];
    unsigned b = *(const unsigned*)&t16[(n + 1) * 136 + p * 2];
    lo[u] = (a & 0xFFFFu) | (b << 16);
    hi[u] = (a >> 16) | (b & 0xFFFF0000u);
  }
  uint4* d0 = (uint4*)(b1hT + (size_t)(e0 + 2 * p) * NN + n0 + h * 32);
  d0[0] = make_uint4(lo[0], lo[1], lo[2], lo[3]);
  d0[1] = make_uint4(lo[4], lo[5], lo[6], lo[7]);
  d0[2] = make_uint4(lo[8], lo[9], lo[10], lo[11]);
  d0[3] = make_uint4(lo[12], lo[13], lo[14], lo[15]);
  uint4* d1 = (uint4*)(b1hT + (size_t)(e0 + 2 * p + 1) * NN + n0 + h * 32);
  d1[0] = make_uint4(hi[0], hi[1], hi[2], hi[3]);
  d1[1] = make_uint4(hi[4], hi[5], hi[6], hi[7]);
  d1[2] = make_uint4(hi[8], hi[9], hi[10], hi[11]);
  d1[3] = make_uint4(hi[12], hi[13], hi[14], hi[15]);
}

// ---------------- K2: y0 GEMM + scaled transpose epilogue ----------------
__global__ __launch_bounds__(256) void k2_y0(const float* __restrict__ X0,
                                             const unsigned short* __restrict__ W0T,
                                             const float* __restrict__ rowsum,
                                             unsigned short* __restrict__ y0sT) {
  __shared__ unsigned short a_lds[64 * 32];
  __shared__ unsigned short b_lds[256 * 32];
  const int tid = threadIdx.x;
  const int wave = tid >> 6, lane = tid & 63;
  const int quad = lane >> 4, l15 = lane & 15;
  const int m0 = blockIdx.x * 64;
  const int ar = tid >> 3, ac = (tid & 7) * 4;

  f32x4 acc[4][4];
  const f32x4 fz = {0.f, 0.f, 0.f, 0.f};
#pragma unroll
  for (int i = 0; i < 4; ++i)
#pragma unroll
    for (int j = 0; j < 4; ++j) acc[i][j] = fz;

  for (int k0 = 0; k0 < CH; k0 += 32) {
    __syncthreads();
#pragma unroll
    for (int p = 0; p < 2; ++p) {
      float4 v = *(const float4*)(X0 + (size_t)(m0 + ar + p * 32) * CH + k0 + ac);
      uint2 w;
      w.x = ((unsigned)f2bf(v.x)) | ((unsigned)f2bf(v.y) << 16);
      w.y = ((unsigned)f2bf(v.z)) | ((unsigned)f2bf(v.w) << 16);
      *(uint2*)&a_lds[(ar + p * 32) * 32 + ac] = w;
    }
#pragma unroll
    for (int i = 0; i < 4; ++i) {
      int rowbase = wave * 64 + i * 16;
      const unsigned short* g = W0T + (size_t)(rowbase + (lane >> 2)) * CH + k0 + (lane & 3) * 8;
      async_copy16(g, &b_lds[rowbase * 32]);
    }
    __syncthreads();
    bf16x8 af[4];
#pragma unroll
    for (int i = 0; i < 4; ++i)
      af[i] = *(const bf16x8*)&a_lds[(i * 16 + l15) * 32 + quad * 8];
#pragma unroll
    for (int j = 0; j < 4; ++j) {
      bf16x8 bfr = *(const bf16x8*)&b_lds[(wave * 64 + j * 16 + l15) * 32 + quad * 8];
#pragma unroll
      for (int i = 0; i < 4; ++i)
        acc[i][j] = __builtin_amdgcn_mfma_f32_16x16x32_bf16(af[i], bfr, acc[i][j], 0, 0, 0);
    }
  }
#pragma unroll
  for (int i = 0; i < 4; ++i) {
    int row4 = m0 + i * 16 + quad * 4;
    float4 rsv = *(const float4*)(rowsum + row4);
    float4 nc;
    nc.x = rsqrtf(rsv.x); nc.y = rsqrtf(rsv.y); nc.z = rsqrtf(rsv.z); nc.w = rsqrtf(rsv.w);
#pragma unroll
    for (int j = 0; j < 4; ++j) {
      int col = wave * 64 + j * 16 + l15;
      f32x4 v = acc[i][j];
      ushort4 o;
      o.x = f2bf(v[0] * nc.x);
      o.y = f2bf(v[1] * nc.y);
      o.z = f2bf(v[2] * nc.z);
      o.w = f2bf(v[3] * nc.w);
      *(ushort4*)&y0sT[(size_t)col * NN + row4] = o;
    }
  }
}

// ---------------- K2b: y0sT aux rows ----------------
__global__ void k2b_aux(const float* __restrict__ rowsum, unsigned short* __restrict__ y0sT) {
  int n = blockIdx.x * 256 + threadIdx.x;
  y0sT[(size_t)256 * NN + n] = f2bf(rsqrtf(rowsum[n]));
  y0sT[(size_t)257 * NN + n] = 0x3F80;  // 1.0 bf16
#pragma unroll
  for (int r = 258; r < 272; ++r) y0sT[(size_t)r * NN + n] = 0;
}

// ------- MM core v4: outT[sp][272][NSZ] = Y(272 x K) @ stream(NSZ x K) -----------
// Pure register pipeline. Wave tile = TM(8/9) m-tiles x 32 n. A-frags (Y, L2) and
// B-frags (stream) per-lane 16B loads; B rotated 4-deep (unroll4, it&3), A 2-deep.
// No LDS, no barriers -> compiler emits exact vmcnt(N); deep prefetch survives.
template <int K, int NSZ, int SPLIT, bool F32S>
__device__ __forceinline__ void mm_core_reg(const unsigned short* __restrict__ Y,
                                            const void* __restrict__ BmV,
                                            float* __restrict__ outp,
                                            int sp, int mb, int nb) {
  constexpr int KS = K / SPLIT;
  constexpr int STEPS = KS / 32;
  const int tid = threadIdx.x;
  const int wave = tid >> 6, lane = tid & 63;
  const int quad = lane >> 4, l15 = lane & 15;
  const int TM = mb ? 8 : 9, mtb = mb ? 9 : 0;
  const int n0 = nb * 128 + wave * 32;
  const int kb0 = sp * KS;
  const char* Yb = (const char*)Y;
  const char* Bb = (const char*)BmV;

  f32x4 acc[9][2];
  const f32x4 fz = {0.f, 0.f, 0.f, 0.f};
#pragma unroll
  for (int i = 0; i < 9; ++i)
#pragma unroll
    for (int j = 0; j < 2; ++j) acc[i][j] = fz;

  unsigned voffA[9];
#pragma unroll
  for (int i = 0; i < 9; ++i)
    voffA[i] = (unsigned)(((mtb + i) * 16 + l15) * K) * 2u + quad * 16;
  unsigned voffB[2];
#pragma unroll
  for (int j = 0; j < 2; ++j) {
    unsigned row = (unsigned)(n0 + j * 16 + l15);
    voffB[j] = F32S ? (row * (unsigned)K * 4u + quad * 32) : (row * (unsigned)K * 2u + quad * 16);
  }

  bf16x8 Ar[2][9];
  float4 Brf[4][2][2];  // fp32 stream regs (F32S)
  bf16x8 Brh[4][2];     // bf16 stream regs (!F32S)

  auto loadA = [&](int it, int slot) {
    unsigned kb = (unsigned)(kb0 + it * 32) * 2u;
#pragma unroll
    for (int i = 0; i < 9; ++i)
      if (i < TM) Ar[slot][i] = *(const bf16x8*)(Yb + voffA[i] + kb);
  };
  auto loadB = [&](int it, int slot) {
    if constexpr (F32S) {
      unsigned kb = (unsigned)(kb0 + it * 32) * 4u;
#pragma unroll
      for (int j = 0; j < 2; ++j) {
        Brf[slot][j][0] = *(const float4*)(Bb + voffB[j] + kb);
        Brf[slot][j][1] = *(const float4*)(Bb + voffB[j] + kb + 16);
      }
    } else {
      unsigned kb = (unsigned)(kb0 + it * 32) * 2u;
#pragma unroll
      for (int j = 0; j < 2; ++j) Brh[slot][j] = *(const bf16x8*)(Bb + voffB[j] + kb);
    }
  };

#pragma unroll
  for (int p = 0; p < 4; ++p) loadB(p, p);
#pragma unroll
  for (int p = 0; p < 2; ++p) loadA(p, p);

#pragma unroll 4
  for (int it = 0; it < STEPS; ++it) {
    const int as = it & 1, bs = it & 3;
#pragma unroll
    for (int j = 0; j < 2; ++j) {
      bf16x8 bj;
      if constexpr (F32S) {
        const unsigned* u = (const unsigned*)&Brf[bs][j][0];
        unsigned w[4];
        w[0] = (u[0] >> 16) | (u[1] & 0xFFFF0000u);
        w[1] = (u[2] >> 16) | (u[3] & 0xFFFF0000u);
        w[2] = (u[4] >> 16) | (u[5] & 0xFFFF0000u);
        w[3] = (u[6] >> 16) | (u[7] & 0xFFFF0000u);
        bj = *(const bf16x8*)w;
      } else {
        bj = Brh[bs][j];
      }
#pragma unroll
      for (int i = 0; i < 9; ++i)
        if (i < TM) acc[i][j] = __builtin_amdgcn_mfma_f32_16x16x32_bf16(Ar[as][i], bj, acc[i][j], 0, 0, 0);
    }
    int ita = it + 2; if (ita >= STEPS) ita = STEPS - 1;
    loadA(ita, as);
    int itb = it + 4; if (itb >= STEPS) itb = STEPS - 1;
    loadB(itb, bs);
  }

  float* op = outp + (size_t)sp * 272 * NSZ;
#pragma unroll
  for (int i = 0; i < 9; ++i) {
    if (i < TM) {
      int c0 = (mtb + i) * 16 + quad * 4;
#pragma unroll
      for (int j = 0; j < 2; ++j) {
        int n = n0 + j * 16 + l15;
#pragma unroll
        for (int r = 0; r < 4; ++r) op[(size_t)(c0 + r) * NSZ + n] = acc[i][j][r];
      }
    }
  }
}

// MM1: bid = sp + 4*(nb&1) + 8*(mb + 2*(nb>>1)); mb-pair 8 apart -> same XCD.
__global__ __launch_bounds__(256, 2) void mm1t_kernel(const unsigned short* __restrict__ y0sT,
                                                      const unsigned short* __restrict__ b1hT,
                                                      float* __restrict__ mm1pT) {
  const int bid = blockIdx.x;
  const int sp = bid & 3;
  const int mb = (bid >> 3) & 1;
  const int nb = ((bid >> 2) & 1) + 2 * (bid >> 4);
  mm_core_reg<NN, NE, MM1_SPLIT, false>(y0sT, b1hT, mm1pT, sp, mb, nb);
}
// MM2: bid = sp + 2*(nb&3) + 8*(mb + 2*(nb>>2)); streams fp32 B1 directly.
__global__ __launch_bounds__(256, 2) void mm2t_kernel(const unsigned short* __restrict__ y1sT,
                                                      const float* __restrict__ B1,
                                                      float* __restrict__ mm2pT) {
  const int bid = blockIdx.x;
  const int sp = bid & 1;
  const int mb = (bid >> 3) & 1;
  const int nb = ((bid >> 1) & 3) + 4 * (bid >> 4);
  mm_core_reg<NE, NN, MM2_SPLIT, true>(y1sT, B1, mm2pT, sp, mb, nb);
}

// ---------------- K3: reduce partials + finalize edges (transpose epilogue) --------
__global__ __launch_bounds__(256) void k3_edge_final(const float* __restrict__ mm1pT,
                                                     const float* __restrict__ b01,
                                                     float* __restrict__ out1,
                                                     unsigned short* __restrict__ x1bf,
                                                     float* __restrict__ edge_card) {
  __shared__ float tile[32 * 260];
  __shared__ float d1s[32], css[32];
  const int tid = threadIdx.x;
  const int e0 = blockIdx.x * 32;
  float p[32];
#pragma unroll
  for (int u = 0; u < 32; ++u) p[u] = 0.f;
  for (int sp = 0; sp < MM1_SPLIT; ++sp) {
    const float4* rp = (const float4*)(mm1pT + ((size_t)sp * 272 + tid) * NE + e0);
#pragma unroll
    for (int u = 0; u < 8; ++u) {
      float4 v = rp[u];
      p[u * 4 + 0] += v.x; p[u * 4 + 1] += v.y; p[u * 4 + 2] += v.z; p[u * 4 + 3] += v.w;
    }
  }
  if (tid < 64) {
    int row = 256 + (tid >> 5), e = e0 + (tid & 31);
    float s = 0.f;
    for (int sp = 0; sp < MM1_SPLIT; ++sp) s += mm1pT[((size_t)sp * 272 + row) * NE + e];
    if (tid < 32) d1s[tid] = s; else css[tid & 31] = s;
  }
  __syncthreads();
  float bc = b01[tid];
#pragma unroll
  for (int u = 0; u < 32; ++u) tile[u * 260 + tid] = p[u] / d1s[u] + bc;
  if (tid < 32) {
    float cs = css[tid];
    edge_card[e0 + tid] = 1.0f / (cs * sqrtf(cs));
  }
  __syncthreads();
  const int e = tid >> 3, cb = (tid & 7) * 32;
  const float* trow = &tile[e * 260 + cb];
  float* orow = out1 + (size_t)(e0 + e) * CH + cb;
  unsigned short* xrow = x1bf + (size_t)(e0 + e) * CH + cb;
#pragma unroll
  for (int v = 0; v < 32; v += 4) {
    float4 x;
    x.x = trow[v]; x.y = trow[v + 1]; x.z = trow[v + 2]; x.w = trow[v + 3];
    float4 rl;
    rl.x = fmaxf(x.x, 0.f); rl.y = fmaxf(x.y, 0.f); rl.z = fmaxf(x.z, 0.f); rl.w = fmaxf(x.w, 0.f);
    *(float4*)&orow[v] = rl;
    ushort4 h;
    h.x = f2bf(x.x); h.y = f2bf(x.y); h.z = f2bf(x.z); h.w = f2bf(x.w);
    *(ushort4*)&xrow[v] = h;
  }
}

// ---------------- K5: y1 GEMM + scaled transpose epilogue ----------------
__global__ __launch_bounds__(256) void k5_y1(const unsigned short* __restrict__ x1bf,
                                             const unsigned short* __restrict__ W1T,
                                             const float* __restrict__ edge_card,
                                             unsigned short* __restrict__ y1sT) {
  __shared__ unsigned short a_lds[64 * 32];
  __shared__ unsigned short b_lds[256 * 32];
  const int tid = threadIdx.x;
  const int wave = tid >> 6, lane = tid & 63;
  const int quad = lane >> 4, l15 = lane & 15;
  const int m0 = blockIdx.x * 64;  // e-range

  f32x4 acc[4][4];
  const f32x4 fz = {0.f, 0.f, 0.f, 0.f};
#pragma unroll
  for (int i = 0; i < 4; ++i)
#pragma unroll
    for (int j = 0; j < 4; ++j) acc[i][j] = fz;

  for (int k0 = 0; k0 < CH; k0 += 32) {
    __syncthreads();
    {
      const unsigned short* g = x1bf + (size_t)(m0 + wave * 16 + (lane >> 2)) * CH + k0 + (lane & 3) * 8;
      async_copy16(g, &a_lds[(wave * 16) * 32]);
    }
#pragma unroll
    for (int i = 0; i < 4; ++i) {
      int rowbase = wave * 64 + i * 16;
      const unsigned short* g = W1T + (size_t)(rowbase + (lane >> 2)) * CH + k0 + (lane & 3) * 8;
      async_copy16(g, &b_lds[rowbase * 32]);
    }
    __syncthreads();
    bf16x8 af[4];
#pragma unroll
    for (int i = 0; i < 4; ++i)
      af[i] = *(const bf16x8*)&a_lds[(i * 16 + l15) * 32 + quad * 8];
#pragma unroll
    for (int j = 0; j < 4; ++j) {
      bf16x8 bfr = *(const bf16x8*)&b_lds[(wave * 64 + j * 16 + l15) * 32 + quad * 8];
#pragma unroll
      for (int i = 0; i < 4; ++i)
        acc[i][j] = __builtin_amdgcn_mfma_f32_16x16x32_bf16(af[i], bfr, acc[i][j], 0, 0, 0);
    }
  }
#pragma unroll
  for (int i = 0; i < 4; ++i) {
    int row4 = m0 + i * 16 + quad * 4;
    float4 ec = *(const float4*)(edge_card + row4);
#pragma unroll
    for (int j = 0; j < 4; ++j) {
      int col = wave * 64 + j * 16 + l15;
      f32x4 v = acc[i][j];
      ushort4 o;
      o.x = f2bf(v[0] * ec.x);
      o.y = f2bf(v[1] * ec.y);
      o.z = f2bf(v[2] * ec.z);
      o.w = f2bf(v[3] * ec.w);
      *(ushort4*)&y1sT[(size_t)col * NE + row4] = o;
    }
  }
}

// ---------------- K5b: y1sT aux rows ----------------
__global__ void k5b_aux(const float* __restrict__ edge_card, unsigned short* __restrict__ y1sT) {
  int e = blockIdx.x * 256 + threadIdx.x;
  y1sT[(size_t)256 * NE + e] = f2bf(edge_card[e]);
#pragma unroll
  for (int r = 257; r < 272; ++r) y1sT[(size_t)r * NE + e] = 0;
}

// ---------------- K6: reduce partials + finalize nodes (transpose epilogue) --------
__global__ __launch_bounds__(256) void k6_node_final(const float* __restrict__ mm2pT,
                                                     const float* __restrict__ b10,
                                                     float* __restrict__ out0) {
  __shared__ float tile[32 * 260];
  __shared__ float d0s[32];
  const int tid = threadIdx.x;
  const int n0 = blockIdx.x * 32;
  float p[32];
#pragma unroll
  for (int u = 0; u < 32; ++u) p[u] = 0.f;
  for (int sp = 0; sp < MM2_SPLIT; ++sp) {
    const float4* rp = (const float4*)(mm2pT + ((size_t)sp * 272 + tid) * NN + n0);
#pragma unroll
    for (int u = 0; u < 8; ++u) {
      float4 v = rp[u];
      p[u * 4 + 0] += v.x; p[u * 4 + 1] += v.y; p[u * 4 + 2] += v.z; p[u * 4 + 3] += v.w;
    }
  }
  if (tid < 32) {
    float s = 0.f;
    for (int sp = 0; sp < MM2_SPLIT; ++sp) s += mm2pT[((size_t)sp * 272 + 256) * NN + n0 + tid];
    d0s[tid] = s;
  }
  __syncthreads();
  float bc = b10[tid];
#pragma unroll
  for (int u = 0; u < 32; ++u) tile[u * 260 + tid] = p[u] / d0s[u] + bc;
  __syncthreads();
  const int n = tid >> 3, cb = (tid & 7) * 32;
  const float* trow = &tile[n * 260 + cb];
  float* orow = out0 + (size_t)(n0 + n) * CH + cb;
#pragma unroll
  for (int v = 0; v < 32; v += 4) {
    float4 x;
    x.x = trow[v]; x.y = trow[v + 1]; x.z = trow[v + 2]; x.w = trow[v + 3];
    float4 rl;
    rl.x = fmaxf(x.x, 0.f); rl.y = fmaxf(x.y, 0.f); rl.z = fmaxf(x.z, 0.f); rl.w = fmaxf(x.w, 0.f);
    *(float4*)&orow[v] = rl;
  }
}

extern "C" void kernel_launch(void* const* d_in, const int* in_sizes, int n_in,
                              void* d_out, int out_size, void* d_ws, size_t ws_size,
                              hipStream_t stream) {
  const float* x0 = (const float*)d_in[0];
  const float* B1 = (const float*)d_in[1];
  const float* W0 = (const float*)d_in[2];
  const float* W1 = (const float*)d_in[3];
  const float* b01 = (const float*)d_in[4];
  const float* b10 = (const float*)d_in[5];
  float* out0 = (float*)d_out;
  float* out1 = out0 + (size_t)NN * CH;

  char* ws = (char*)d_ws;
  size_t off = 0;
  auto take = [&](size_t bytes) {
    void* p = ws + off;
    off += (bytes + 255) & ~(size_t)255;
    return p;
  };
  unsigned short* b1hT = (unsigned short*)take((size_t)NN * NE * 2);   // 268 MB [e][n]
  unsigned short* y0sT = (unsigned short*)take((size_t)272 * NN * 2);  // 8.9 MB
  unsigned short* y1sT = (unsigned short*)take((size_t)272 * NE * 2);  // 4.5 MB
  unsigned short* x1bf = (unsigned short*)take((size_t)NE * CH * 2);   // 4.2 MB
  float* mm1pT = (float*)take((size_t)MM1_SPLIT * 272 * NE * 4);       // 35.7 MB
  float* mm2pT = mm1pT;  // alias: mm1pT dead after K3; MM2_SPLIT*272*NN*4 same size
  float* rowsum = (float*)take((size_t)NN * 4);
  float* edge_card = (float*)take((size_t)NE * 4);
  unsigned short* W0T = (unsigned short*)take((size_t)CH * CH * 2);
  unsigned short* W1T = (unsigned short*)take((size_t)CH * CH * 2);
  (void)ws_size; (void)in_sizes; (void)n_in; (void)out_size;

  k0_transpose_w<<<dim3(256, 2), 256, 0, stream>>>(W0, W1, W0T, W1T, rowsum);
  k1_prep<<<dim3(NE / 128, NN / 128), 256, 0, stream>>>(B1, b1hT, rowsum);
  k2_y0<<<NN / 64, 256, 0, stream>>>(x0, W0T, rowsum, y0sT);
  k2b_aux<<<NN / 256, 256, 0, stream>>>(rowsum, y0sT);
  mm1t_kernel<<<(NE / 128) * 2 * MM1_SPLIT, 256, 0, stream>>>(y0sT, b1hT, mm1pT);
  k3_edge_final<<<NE / 32, 256, 0, stream>>>(mm1pT, b01, out1, x1bf, edge_card);
  k5_y1<<<NE / 64, 256, 0, stream>>>(x1bf, W1T, edge_card, y1sT);
  k5b_aux<<<NE / 256, 256, 0, stream>>>(edge_card, y1sT);
  mm2t_kernel<<<(NN / 128) * 2 * MM2_SPLIT, 256, 0, stream>>>(y1sT, B1, mm2pT);
  k6_node_final<<<NN / 32, 256, 0, stream>>>(mm2pT, b10, out0);
}